// Round 8
// baseline (162.677 us; speedup 1.0000x reference)
//
#include <hip/hip_runtime.h>
#include <hip/hip_bf16.h>

typedef __attribute__((ext_vector_type(8))) short short8;
typedef __attribute__((ext_vector_type(4))) short short4v;
typedef __attribute__((ext_vector_type(4))) float f32x4;

#define MFMA16(A, B, C) __builtin_amdgcn_mfma_f32_16x16x32_bf16(A, B, C, 0, 0, 0)

#define SEQ 2048
#define DM 512
#define NH 8
#define DK 64
#define NROWS 4096   // B*S
#define DSPLIT 4     // k-splits for den
#define ASPLIT 2     // k-splits for attn_pv
#define NT_D (SEQ / DSPLIT / 64)  // 8 tiles
#define NT_A (SEQ / ASPLIT / 64)  // 16 tiles
#define C1 0.180336880f           // 0.125 * log2(e)

__device__ __forceinline__ short f2bf(float f) {
  union { float f; unsigned u; } x; x.f = f;
  unsigned r = (x.u + 0x7fffu + ((x.u >> 16) & 1u)) >> 16;
  return (short)r;
}
__device__ __forceinline__ float bf2f(short s) {
  union { unsigned u; float f; } x; x.u = ((unsigned)(unsigned short)s) << 16;
  return x.f;
}

// ---------------------------------------------------------------------------
// Kernel 0a/0b: one-time f32 -> bf16 casts
// ---------------------------------------------------------------------------
__global__ __launch_bounds__(256) void cast3_kernel(
    const float* __restrict__ a, const float* __restrict__ b, const float* __restrict__ c,
    short* __restrict__ ab, short* __restrict__ bb, short* __restrict__ cb)
{
  int z = blockIdx.z;
  const float* src = (z == 0) ? a : (z == 1) ? b : c;
  short* dst = (z == 0) ? ab : (z == 1) ? bb : cb;
  size_t i = ((size_t)blockIdx.x * 256 + threadIdx.x) * 8;
  float4 f0 = *(const float4*)(src + i);
  float4 f1 = *(const float4*)(src + i + 4);
  short8 s;
  s[0] = f2bf(f0.x); s[1] = f2bf(f0.y); s[2] = f2bf(f0.z); s[3] = f2bf(f0.w);
  s[4] = f2bf(f1.x); s[5] = f2bf(f1.y); s[6] = f2bf(f1.z); s[7] = f2bf(f1.w);
  *(short8*)(dst + i) = s;
}

__global__ __launch_bounds__(256) void cast4_kernel(
    const float* __restrict__ a, const float* __restrict__ b,
    const float* __restrict__ c, const float* __restrict__ d,
    short* __restrict__ ab, short* __restrict__ bb,
    short* __restrict__ cb, short* __restrict__ db)
{
  int z = blockIdx.z;
  const float* src = (z == 0) ? a : (z == 1) ? b : (z == 2) ? c : d;
  short* dst = (z == 0) ? ab : (z == 1) ? bb : (z == 2) ? cb : db;
  size_t i = ((size_t)blockIdx.x * 256 + threadIdx.x) * 8;
  float4 f0 = *(const float4*)(src + i);
  float4 f1 = *(const float4*)(src + i + 4);
  short8 s;
  s[0] = f2bf(f0.x); s[1] = f2bf(f0.y); s[2] = f2bf(f0.z); s[3] = f2bf(f0.w);
  s[4] = f2bf(f1.x); s[5] = f2bf(f1.y); s[6] = f2bf(f1.z); s[7] = f2bf(f1.w);
  *(short8*)(dst + i) = s;
}

// ---------------------------------------------------------------------------
// Kernel 1: QKV projection (bf16 inputs), register-prefetched staging.
// ---------------------------------------------------------------------------
__global__ __launch_bounds__(256) void qkv_proj_kernel(
    const short* __restrict__ qbf, const short* __restrict__ kbf, const short* __restrict__ vbf,
    const short* __restrict__ Wqb, const short* __restrict__ Wkb, const short* __restrict__ Wvb,
    const float* __restrict__ bq, const float* __restrict__ bk, const float* __restrict__ bv,
    short* __restrict__ Qb, short* __restrict__ Kb, short* __restrict__ Vtb)
{
  int z = blockIdx.z;
  const short* X    = (z == 0) ? qbf : (z == 1) ? kbf : vbf;
  const short* W    = (z == 0) ? Wqb : (z == 1) ? Wkb : Wvb;
  const float* bias = (z == 0) ? bq  : (z == 1) ? bk  : bv;

  __shared__ short As[64][40];
  __shared__ short Bs[64][40];

  int t = threadIdx.x;
  int lane = t & 63, wave = t >> 6;
  int wr = wave >> 1, wc = wave & 1;
  int fr = lane & 15, fg = lane >> 4;
  int m0 = blockIdx.x * 64, n0 = blockIdx.y * 64;
  int lrow = t >> 2, lcol = (t & 3) * 8;

  f32x4 acc[2][2] = {};

  short8 a_pf = *(const short8*)(X + (size_t)(m0 + lrow) * DM + lcol);
  short8 b_pf = *(const short8*)(W + (size_t)(n0 + lrow) * DM + lcol);

  for (int k0 = 0; k0 < DM; k0 += 32) {
    __syncthreads();
    *(short8*)&As[lrow][lcol] = a_pf;
    *(short8*)&Bs[lrow][lcol] = b_pf;
    __syncthreads();
    if (k0 + 32 < DM) {
      a_pf = *(const short8*)(X + (size_t)(m0 + lrow) * DM + k0 + 32 + lcol);
      b_pf = *(const short8*)(W + (size_t)(n0 + lrow) * DM + k0 + 32 + lcol);
    }
    short8 a0 = *(const short8*)&As[wr * 32 + fr][fg * 8];
    short8 a1 = *(const short8*)&As[wr * 32 + 16 + fr][fg * 8];
    short8 b0 = *(const short8*)&Bs[wc * 32 + fr][fg * 8];
    short8 b1 = *(const short8*)&Bs[wc * 32 + 16 + fr][fg * 8];
    acc[0][0] = MFMA16(a0, b0, acc[0][0]);
    acc[0][1] = MFMA16(a0, b1, acc[0][1]);
    acc[1][0] = MFMA16(a1, b0, acc[1][0]);
    acc[1][1] = MFMA16(a1, b1, acc[1][1]);
  }

#pragma unroll
  for (int mi = 0; mi < 2; mi++)
#pragma unroll
    for (int ni = 0; ni < 2; ni++)
#pragma unroll
      for (int r = 0; r < 4; r++) {
        int row = m0 + wr * 32 + mi * 16 + fg * 4 + r;
        int col = n0 + wc * 32 + ni * 16 + fr;
        float val = acc[mi][ni][r] + bias[col];
        int bb = row >> 11, s = row & 2047, h = col >> 6, dk = col & 63;
        short o = f2bf(val);
        if (z == 0)      Qb[((size_t)(bb * NH + h) * SEQ + s) * DK + dk] = o;
        else if (z == 1) Kb[((size_t)(bb * NH + h) * SEQ + s) * DK + dk] = o;
        else             Vtb[((size_t)(bb * NH + h) * DK + dk) * SEQ + s] = o;
      }
}

// ---------------------------------------------------------------------------
// Kernel 2a: softmax denominators (M=0), swapped QK: lane owns one q-row.
// dp[z][bh][row] = sum_{k in split z} exp2(score*C1)
// ---------------------------------------------------------------------------
__global__ __launch_bounds__(256) void den_kernel(
    const short* __restrict__ Q, const short* __restrict__ K, float* __restrict__ dp)
{
  __shared__ short Ks[64][72];

  int t = threadIdx.x, lane = t & 63, wave = t >> 6;
  int fr = lane & 15, fg = lane >> 4;
  int bh = blockIdx.y, z = blockIdx.z;
  const short* Qh = Q + (size_t)bh * SEQ * DK;
  const short* Kh = K + (size_t)bh * SEQ * DK;
  int q0 = blockIdx.x * 64 + wave * 16;
  const int kbase = z * (SEQ / DSPLIT);

  short8 qa0 = *(const short8*)(Qh + (q0 + fr) * DK + fg * 8);
  short8 qa1 = *(const short8*)(Qh + (q0 + fr) * DK + 32 + fg * 8);

  int r_st = t >> 2, c_st = (t & 3) * 16;

  const short* kp0 = Kh + (size_t)(kbase + r_st) * DK + c_st;
  short8 k_pf0 = *(const short8*)kp0;
  short8 k_pf1 = *(const short8*)(kp0 + 8);

  float esum = 0.f;

  for (int kt = 0; kt < NT_D; kt++) {
    __syncthreads();
    *(short8*)&Ks[r_st][c_st]     = k_pf0;
    *(short8*)&Ks[r_st][c_st + 8] = k_pf1;
    __syncthreads();
    if (kt + 1 < NT_D) {
      const short* kp = Kh + (size_t)(kbase + (kt + 1) * 64 + r_st) * DK + c_st;
      k_pf0 = *(const short8*)kp;
      k_pf1 = *(const short8*)(kp + 8);
    }
#pragma unroll
    for (int ct = 0; ct < 4; ct++) {
      short8 k0v = *(const short8*)&Ks[ct * 16 + fr][fg * 8];
      short8 k1v = *(const short8*)&Ks[ct * 16 + fr][32 + fg * 8];
      f32x4 zz = {0.f, 0.f, 0.f, 0.f};
      zz = MFMA16(k0v, qa0, zz);   // swapped: lane -> q-row fr, k-cols fg*4+r
      zz = MFMA16(k1v, qa1, zz);
#pragma unroll
      for (int r = 0; r < 4; r++)
        esum += __builtin_amdgcn_exp2f(zz[r] * C1);
    }
  }

  esum += __shfl_xor(esum, 16);
  esum += __shfl_xor(esum, 32);
  if (lane < 16)
    dp[((size_t)z * 16 + bh) * SEQ + q0 + lane] = esum;
}

// ---------------------------------------------------------------------------
// Kernel 2b: fused attention: swapped QK -> direct-from-register NT attn
// stores (f32, 16B/lane) + bf16 P (packed b64 LDS writes) -> PV accumulate.
// ---------------------------------------------------------------------------
__global__ __launch_bounds__(256) void attn_pv_kernel(
    const short* __restrict__ Q, const short* __restrict__ K, const short* __restrict__ Vt,
    const float* __restrict__ dp, float* __restrict__ attn, short* __restrict__ ctxp)
{
  __shared__ short Ks[64][72];
  __shared__ short Vs[64][72];
  __shared__ short P[4][16][72];

  int t = threadIdx.x, lane = t & 63, wave = t >> 6;
  int fr = lane & 15, fg = lane >> 4;
  int bh = blockIdx.y, z = blockIdx.z;
  const short* Qh = Q + (size_t)bh * SEQ * DK;
  const short* Kh = K + (size_t)bh * SEQ * DK;
  const short* Vh = Vt + (size_t)bh * DK * SEQ;
  int q0 = blockIdx.x * 64 + wave * 16;
  const int kbase = z * (SEQ / ASPLIT);

  short8 qa0 = *(const short8*)(Qh + (q0 + fr) * DK + fg * 8);
  short8 qa1 = *(const short8*)(Qh + (q0 + fr) * DK + 32 + fg * 8);

  // per-lane denominator for q-row fr; fold 1/d into exp2 as +log2(1/d)
  float dsum = 0.f;
#pragma unroll
  for (int zz = 0; zz < DSPLIT; zz++)
    dsum += dp[((size_t)zz * 16 + bh) * SEQ + q0 + fr];
  float lg2r = -__builtin_amdgcn_logf(dsum);

  int r_st = t >> 2, c_st = (t & 3) * 16;

  f32x4 oacc[4] = {};

  const short* kp0 = Kh + (size_t)(kbase + r_st) * DK + c_st;
  const short* vp0 = Vh + (size_t)r_st * SEQ + kbase + c_st;
  short8 k_pf0 = *(const short8*)kp0;
  short8 k_pf1 = *(const short8*)(kp0 + 8);
  short8 v_pf0 = *(const short8*)vp0;
  short8 v_pf1 = *(const short8*)(vp0 + 8);

  for (int kt = 0; kt < NT_A; kt++) {
    int kb = kbase + kt * 64;
    __syncthreads();
    *(short8*)&Ks[r_st][c_st]     = k_pf0;
    *(short8*)&Ks[r_st][c_st + 8] = k_pf1;
    *(short8*)&Vs[r_st][c_st]     = v_pf0;
    *(short8*)&Vs[r_st][c_st + 8] = v_pf1;
    __syncthreads();
    if (kt + 1 < NT_A) {
      const short* kp = Kh + (size_t)(kb + 64 + r_st) * DK + c_st;
      const short* vp = Vh + (size_t)r_st * SEQ + kb + 64 + c_st;
      k_pf0 = *(const short8*)kp;
      k_pf1 = *(const short8*)(kp + 8);
      v_pf0 = *(const short8*)vp;
      v_pf1 = *(const short8*)(vp + 8);
    }

#pragma unroll
    for (int ct = 0; ct < 4; ct++) {
      short8 k0v = *(const short8*)&Ks[ct * 16 + fr][fg * 8];
      short8 k1v = *(const short8*)&Ks[ct * 16 + fr][32 + fg * 8];
      f32x4 zz = {0.f, 0.f, 0.f, 0.f};
      zz = MFMA16(k0v, qa0, zz);   // swapped: lane -> q-row fr, k fg*4+r
      zz = MFMA16(k1v, qa1, zz);
      // p = exp2(score*C1 + log2(1/den)) : normalized, f32
      f32x4 p;
#pragma unroll
      for (int r = 0; r < 4; r++)
        p[r] = __builtin_amdgcn_exp2f(zz[r] * C1 + lg2r);
      // direct NT store: row q0+fr, cols kb+ct*16+fg*4 .. +3 (16B/lane)
      __builtin_nontemporal_store(p,
          (f32x4*)&attn[((size_t)(bh * SEQ + q0 + fr)) * SEQ + kb + ct * 16 + fg * 4]);
      // stage bf16 P for PV: one packed 8B write
      short4v pk;
#pragma unroll
      for (int r = 0; r < 4; r++) pk[r] = f2bf(p[r]);
      *(short4v*)&P[wave][fr][ct * 16 + fg * 4] = pk;
    }
    asm volatile("s_waitcnt lgkmcnt(0)" ::: "memory");

    // PV: oacc[dt] += P(16q x 64k) * V^T(64d x 64k); 8 MFMAs
    short8 pa0 = *(const short8*)&P[wave][fr][fg * 8];
    short8 pa1 = *(const short8*)&P[wave][fr][32 + fg * 8];
#pragma unroll
    for (int dt = 0; dt < 4; dt++) {
      short8 v0 = *(const short8*)&Vs[dt * 16 + fr][fg * 8];
      short8 v1 = *(const short8*)&Vs[dt * 16 + fr][32 + fg * 8];
      oacc[dt] = MFMA16(pa0, v0, oacc[dt]);
      oacc[dt] = MFMA16(pa1, v1, oacc[dt]);
    }
  }

  int b = bh >> 3, h = bh & 7;
#pragma unroll
  for (int dt = 0; dt < 4; dt++)
#pragma unroll
    for (int r = 0; r < 4; r++) {
      int row = q0 + fg * 4 + r;
      ctxp[((size_t)z * NROWS + (size_t)b * SEQ + row) * DM + h * 64 + dt * 16 + fr] =
          f2bf(oacc[dt][r]);
    }
}

// ---------------------------------------------------------------------------
// Kernel 3: output projection + bias + residual -> x (f32), fused ctx reduce.
// ---------------------------------------------------------------------------
__global__ __launch_bounds__(256) void oproj_kernel(
    const short* __restrict__ ctxp, const short* __restrict__ Wob,
    const float* __restrict__ bias, const float* __restrict__ resid,
    float* __restrict__ xout)
{
  const size_t NPART = (size_t)NROWS * DM;
  __shared__ short As[64][40];
  __shared__ short Bs[64][40];

  int t = threadIdx.x;
  int lane = t & 63, wave = t >> 6;
  int wr = wave >> 1, wc = wave & 1;
  int fr = lane & 15, fg = lane >> 4;
  int m0 = blockIdx.x * 64, n0 = blockIdx.y * 64;
  int lrow = t >> 2, lcol = (t & 3) * 8;

  f32x4 acc[2][2] = {};

  size_t ia0 = (size_t)(m0 + lrow) * DM + lcol;
  short8 a_pf0 = *(const short8*)(ctxp + ia0);
  short8 a_pf1 = *(const short8*)(ctxp + NPART + ia0);
  short8 b_pf = *(const short8*)(Wob + (size_t)(n0 + lrow) * DM + lcol);

  for (int k0 = 0; k0 < DM; k0 += 32) {
    __syncthreads();
    {
      short8 sv;
#pragma unroll
      for (int j = 0; j < 8; j++)
        sv[j] = f2bf(bf2f(a_pf0[j]) + bf2f(a_pf1[j]));
      *(short8*)&As[lrow][lcol] = sv;
      *(short8*)&Bs[lrow][lcol] = b_pf;
    }
    __syncthreads();
    if (k0 + 32 < DM) {
      size_t ia = (size_t)(m0 + lrow) * DM + k0 + 32 + lcol;
      a_pf0 = *(const short8*)(ctxp + ia);
      a_pf1 = *(const short8*)(ctxp + NPART + ia);
      b_pf = *(const short8*)(Wob + (size_t)(n0 + lrow) * DM + k0 + 32 + lcol);
    }
    short8 a0 = *(const short8*)&As[wr * 32 + fr][fg * 8];
    short8 a1 = *(const short8*)&As[wr * 32 + 16 + fr][fg * 8];
    short8 b0 = *(const short8*)&Bs[wc * 32 + fr][fg * 8];
    short8 b1 = *(const short8*)&Bs[wc * 32 + 16 + fr][fg * 8];
    acc[0][0] = MFMA16(a0, b0, acc[0][0]);
    acc[0][1] = MFMA16(a0, b1, acc[0][1]);
    acc[1][0] = MFMA16(a1, b0, acc[1][0]);
    acc[1][1] = MFMA16(a1, b1, acc[1][1]);
  }

#pragma unroll
  for (int mi = 0; mi < 2; mi++)
#pragma unroll
    for (int ni = 0; ni < 2; ni++)
#pragma unroll
      for (int r = 0; r < 4; r++) {
        int row = m0 + wr * 32 + mi * 16 + fg * 4 + r;
        int col = n0 + wc * 32 + ni * 16 + fr;
        float val = acc[mi][ni][r] + bias[col] + resid[(size_t)row * DM + col];
        xout[(size_t)row * DM + col] = val;
      }
}

// ---------------------------------------------------------------------------
// Kernel 4: LayerNorm over last dim (512). One wave per row.
// ---------------------------------------------------------------------------
__global__ __launch_bounds__(256) void ln_kernel(
    const float* __restrict__ x, const float* __restrict__ gamma,
    const float* __restrict__ beta, float* __restrict__ y)
{
  int row = blockIdx.x * 4 + (threadIdx.x >> 6);
  int lane = threadIdx.x & 63;
  const float4* xr = (const float4*)(x + (size_t)row * DM);
  float4 v0 = xr[lane * 2];
  float4 v1 = xr[lane * 2 + 1];
  float s = v0.x + v0.y + v0.z + v0.w + v1.x + v1.y + v1.z + v1.w;
#pragma unroll
  for (int off = 1; off < 64; off <<= 1) s += __shfl_xor(s, off);
  float mean = s * (1.0f / DM);
  float a0 = v0.x - mean, a1 = v0.y - mean, a2 = v0.z - mean, a3 = v0.w - mean;
  float a4 = v1.x - mean, a5 = v1.y - mean, a6 = v1.z - mean, a7 = v1.w - mean;
  float vs = a0 * a0 + a1 * a1 + a2 * a2 + a3 * a3 + a4 * a4 + a5 * a5 + a6 * a6 + a7 * a7;
#pragma unroll
  for (int off = 1; off < 64; off <<= 1) vs += __shfl_xor(vs, off);
  float rstd = rsqrtf(vs * (1.0f / DM) + 1e-5f);
  const float4* gp = (const float4*)gamma;
  const float4* bp = (const float4*)beta;
  float4 g0 = gp[lane * 2], g1 = gp[lane * 2 + 1];
  float4 b0 = bp[lane * 2], b1 = bp[lane * 2 + 1];
  float4 o0, o1;
  o0.x = a0 * rstd * g0.x + b0.x; o0.y = a1 * rstd * g0.y + b0.y;
  o0.z = a2 * rstd * g0.z + b0.z; o0.w = a3 * rstd * g0.w + b0.w;
  o1.x = a4 * rstd * g1.x + b1.x; o1.y = a5 * rstd * g1.y + b1.y;
  o1.z = a6 * rstd * g1.z + b1.z; o1.w = a7 * rstd * g1.w + b1.w;
  float4* yr = (float4*)(y + (size_t)row * DM);
  yr[lane * 2] = o0;
  yr[lane * 2 + 1] = o1;
}

// ---------------------------------------------------------------------------
extern "C" void kernel_launch(void* const* d_in, const int* in_sizes, int n_in,
                              void* d_out, int out_size, void* d_ws, size_t ws_size,
                              hipStream_t stream)
{
  const float* q     = (const float*)d_in[0];
  const float* k     = (const float*)d_in[1];
  const float* v     = (const float*)d_in[2];
  const float* Wq    = (const float*)d_in[3];
  const float* bq    = (const float*)d_in[4];
  const float* Wk    = (const float*)d_in[5];
  const float* bk    = (const float*)d_in[6];
  const float* Wv    = (const float*)d_in[7];
  const float* bv    = (const float*)d_in[8];
  const float* Wo    = (const float*)d_in[9];
  const float* bo    = (const float*)d_in[10];
  const float* gamma = (const float*)d_in[11];
  const float* beta  = (const float*)d_in[12];

  char* w = (char*)d_ws;
  short* qbf  = (short*)(w);                          // [ 0, 4)  bf16 [NROWS][DM]
  short* kbf  = (short*)(w + ((size_t)4  << 20));     // [ 4, 8)
  short* vbf  = (short*)(w + ((size_t)8  << 20));     // [ 8,12)
  short* Qb   = (short*)(w + ((size_t)12 << 20));     // [12,16)  [B,H,S,DK]
  short* Kb   = (short*)(w + ((size_t)16 << 20));     // [16,20)
  short* Vtb  = (short*)(w + ((size_t)20 << 20));     // [20,24)  [B,H,DK,S]
  short* Wqb  = (short*)(w + ((size_t)24 << 20));     // [24,24.5)
  short* Wkb  = (short*)(w + ((size_t)24 << 20) + ((size_t)512 << 10));
  short* Wvb  = (short*)(w + ((size_t)25 << 20));
  short* Wob  = (short*)(w + ((size_t)25 << 20) + ((size_t)512 << 10));
  float* denp = (float*)(w + ((size_t)26 << 20));     // [26,26.5) f32 [4][16][SEQ]
  short* ctxp = (short*)(w);                          // [ 0, 8)  reuse qbf+kbf (dead)
  float* xbuf = (float*)(w + ((size_t)8 << 20));      // [ 8,16)  reuse vbf+Qb (dead)

  float* y = (float*)d_out;
  float* attnp = y + (size_t)NROWS * DM;  // [B,H,S,S]

  cast3_kernel<<<dim3(1024, 1, 3), 256, 0, stream>>>(q, k, v, qbf, kbf, vbf);
  cast4_kernel<<<dim3(128, 1, 4), 256, 0, stream>>>(Wq, Wk, Wv, Wo, Wqb, Wkb, Wvb, Wob);
  qkv_proj_kernel<<<dim3(64, 8, 3), 256, 0, stream>>>(qbf, kbf, vbf, Wqb, Wkb, Wvb,
                                                      bq, bk, bv, Qb, Kb, Vtb);
  den_kernel<<<dim3(32, 16, DSPLIT), 256, 0, stream>>>(Qb, Kb, denp);
  attn_pv_kernel<<<dim3(32, 16, ASPLIT), 256, 0, stream>>>(Qb, Kb, Vtb, denp, attnp, ctxp);
  oproj_kernel<<<dim3(64, 8), 256, 0, stream>>>(ctxp, Wob, bo, q, xbuf);
  ln_kernel<<<1024, 256, 0, stream>>>(xbuf, gamma, beta, y);
}

// Round 9
// 130.179 us; speedup vs baseline: 1.2496x; 1.2496x over previous
//
#include <hip/hip_runtime.h>
#include <hip/hip_bf16.h>

typedef __attribute__((ext_vector_type(8))) short short8;
typedef __attribute__((ext_vector_type(4))) short short4v;
typedef __attribute__((ext_vector_type(4))) float f32x4;

#define MFMA16(A, B, C) __builtin_amdgcn_mfma_f32_16x16x32_bf16(A, B, C, 0, 0, 0)

#define SEQ 2048
#define DM 512
#define NH 8
#define DK 64
#define NROWS 4096   // B*S
#define DSPLIT 4     // k-splits for den
#define ASPLIT 4     // k-splits for attn_pv
#define NT_D (SEQ / DSPLIT / 64)  // 8 tiles
#define NT_A (SEQ / ASPLIT / 64)  // 8 tiles
#define C1 0.180336880f           // 0.125 * log2(e)

__device__ __forceinline__ short f2bf(float f) {
  union { float f; unsigned u; } x; x.f = f;
  unsigned r = (x.u + 0x7fffu + ((x.u >> 16) & 1u)) >> 16;
  return (short)r;
}
__device__ __forceinline__ float bf2f(short s) {
  union { unsigned u; float f; } x; x.u = ((unsigned)(unsigned short)s) << 16;
  return x.f;
}

// ---------------------------------------------------------------------------
// Kernel 0a/0b: one-time f32 -> bf16 casts
// ---------------------------------------------------------------------------
__global__ __launch_bounds__(256) void cast3_kernel(
    const float* __restrict__ a, const float* __restrict__ b, const float* __restrict__ c,
    short* __restrict__ ab, short* __restrict__ bb, short* __restrict__ cb)
{
  int z = blockIdx.z;
  const float* src = (z == 0) ? a : (z == 1) ? b : c;
  short* dst = (z == 0) ? ab : (z == 1) ? bb : cb;
  size_t i = ((size_t)blockIdx.x * 256 + threadIdx.x) * 8;
  float4 f0 = *(const float4*)(src + i);
  float4 f1 = *(const float4*)(src + i + 4);
  short8 s;
  s[0] = f2bf(f0.x); s[1] = f2bf(f0.y); s[2] = f2bf(f0.z); s[3] = f2bf(f0.w);
  s[4] = f2bf(f1.x); s[5] = f2bf(f1.y); s[6] = f2bf(f1.z); s[7] = f2bf(f1.w);
  *(short8*)(dst + i) = s;
}

__global__ __launch_bounds__(256) void cast4_kernel(
    const float* __restrict__ a, const float* __restrict__ b,
    const float* __restrict__ c, const float* __restrict__ d,
    short* __restrict__ ab, short* __restrict__ bb,
    short* __restrict__ cb, short* __restrict__ db)
{
  int z = blockIdx.z;
  const float* src = (z == 0) ? a : (z == 1) ? b : (z == 2) ? c : d;
  short* dst = (z == 0) ? ab : (z == 1) ? bb : (z == 2) ? cb : db;
  size_t i = ((size_t)blockIdx.x * 256 + threadIdx.x) * 8;
  float4 f0 = *(const float4*)(src + i);
  float4 f1 = *(const float4*)(src + i + 4);
  short8 s;
  s[0] = f2bf(f0.x); s[1] = f2bf(f0.y); s[2] = f2bf(f0.z); s[3] = f2bf(f0.w);
  s[4] = f2bf(f1.x); s[5] = f2bf(f1.y); s[6] = f2bf(f1.z); s[7] = f2bf(f1.w);
  *(short8*)(dst + i) = s;
}

// ---------------------------------------------------------------------------
// Kernel 1: QKV projection (bf16 inputs), register-prefetched staging.
// ---------------------------------------------------------------------------
__global__ __launch_bounds__(256) void qkv_proj_kernel(
    const short* __restrict__ qbf, const short* __restrict__ kbf, const short* __restrict__ vbf,
    const short* __restrict__ Wqb, const short* __restrict__ Wkb, const short* __restrict__ Wvb,
    const float* __restrict__ bq, const float* __restrict__ bk, const float* __restrict__ bv,
    short* __restrict__ Qb, short* __restrict__ Kb, short* __restrict__ Vtb)
{
  int z = blockIdx.z;
  const short* X    = (z == 0) ? qbf : (z == 1) ? kbf : vbf;
  const short* W    = (z == 0) ? Wqb : (z == 1) ? Wkb : Wvb;
  const float* bias = (z == 0) ? bq  : (z == 1) ? bk  : bv;

  __shared__ short As[64][40];
  __shared__ short Bs[64][40];

  int t = threadIdx.x;
  int lane = t & 63, wave = t >> 6;
  int wr = wave >> 1, wc = wave & 1;
  int fr = lane & 15, fg = lane >> 4;
  int m0 = blockIdx.x * 64, n0 = blockIdx.y * 64;
  int lrow = t >> 2, lcol = (t & 3) * 8;

  f32x4 acc[2][2] = {};

  short8 a_pf = *(const short8*)(X + (size_t)(m0 + lrow) * DM + lcol);
  short8 b_pf = *(const short8*)(W + (size_t)(n0 + lrow) * DM + lcol);

  for (int k0 = 0; k0 < DM; k0 += 32) {
    __syncthreads();
    *(short8*)&As[lrow][lcol] = a_pf;
    *(short8*)&Bs[lrow][lcol] = b_pf;
    __syncthreads();
    if (k0 + 32 < DM) {
      a_pf = *(const short8*)(X + (size_t)(m0 + lrow) * DM + k0 + 32 + lcol);
      b_pf = *(const short8*)(W + (size_t)(n0 + lrow) * DM + k0 + 32 + lcol);
    }
    short8 a0 = *(const short8*)&As[wr * 32 + fr][fg * 8];
    short8 a1 = *(const short8*)&As[wr * 32 + 16 + fr][fg * 8];
    short8 b0 = *(const short8*)&Bs[wc * 32 + fr][fg * 8];
    short8 b1 = *(const short8*)&Bs[wc * 32 + 16 + fr][fg * 8];
    acc[0][0] = MFMA16(a0, b0, acc[0][0]);
    acc[0][1] = MFMA16(a0, b1, acc[0][1]);
    acc[1][0] = MFMA16(a1, b0, acc[1][0]);
    acc[1][1] = MFMA16(a1, b1, acc[1][1]);
  }

#pragma unroll
  for (int mi = 0; mi < 2; mi++)
#pragma unroll
    for (int ni = 0; ni < 2; ni++)
#pragma unroll
      for (int r = 0; r < 4; r++) {
        int row = m0 + wr * 32 + mi * 16 + fg * 4 + r;
        int col = n0 + wc * 32 + ni * 16 + fr;
        float val = acc[mi][ni][r] + bias[col];
        int bb = row >> 11, s = row & 2047, h = col >> 6, dk = col & 63;
        short o = f2bf(val);
        if (z == 0)      Qb[((size_t)(bb * NH + h) * SEQ + s) * DK + dk] = o;
        else if (z == 1) Kb[((size_t)(bb * NH + h) * SEQ + s) * DK + dk] = o;
        else             Vtb[((size_t)(bb * NH + h) * DK + dk) * SEQ + s] = o;
      }
}

// ---------------------------------------------------------------------------
// Kernel 2a: softmax denominators (M=0), swapped QK (lane owns one q-row;
// no stores in loop, scalar esum, 2 end-shuffles). DSPLIT=4 -> 2048 blocks.
// ---------------------------------------------------------------------------
__global__ __launch_bounds__(256) void den_kernel(
    const short* __restrict__ Q, const short* __restrict__ K, float* __restrict__ dp)
{
  __shared__ short Ks[64][72];

  int t = threadIdx.x, lane = t & 63, wave = t >> 6;
  int fr = lane & 15, fg = lane >> 4;
  int bh = blockIdx.y, z = blockIdx.z;
  const short* Qh = Q + (size_t)bh * SEQ * DK;
  const short* Kh = K + (size_t)bh * SEQ * DK;
  int q0 = blockIdx.x * 64 + wave * 16;
  const int kbase = z * (SEQ / DSPLIT);

  short8 qa0 = *(const short8*)(Qh + (q0 + fr) * DK + fg * 8);
  short8 qa1 = *(const short8*)(Qh + (q0 + fr) * DK + 32 + fg * 8);

  int r_st = t >> 2, c_st = (t & 3) * 16;

  const short* kp0 = Kh + (size_t)(kbase + r_st) * DK + c_st;
  short8 k_pf0 = *(const short8*)kp0;
  short8 k_pf1 = *(const short8*)(kp0 + 8);

  float esum = 0.f;

  for (int kt = 0; kt < NT_D; kt++) {
    __syncthreads();
    *(short8*)&Ks[r_st][c_st]     = k_pf0;
    *(short8*)&Ks[r_st][c_st + 8] = k_pf1;
    __syncthreads();
    if (kt + 1 < NT_D) {
      const short* kp = Kh + (size_t)(kbase + (kt + 1) * 64 + r_st) * DK + c_st;
      k_pf0 = *(const short8*)kp;
      k_pf1 = *(const short8*)(kp + 8);
    }
#pragma unroll
    for (int ct = 0; ct < 4; ct++) {
      short8 k0v = *(const short8*)&Ks[ct * 16 + fr][fg * 8];
      short8 k1v = *(const short8*)&Ks[ct * 16 + fr][32 + fg * 8];
      f32x4 zz = {0.f, 0.f, 0.f, 0.f};
      zz = MFMA16(k0v, qa0, zz);   // swapped: lane -> q-row fr, k-cols fg*4+r
      zz = MFMA16(k1v, qa1, zz);
#pragma unroll
      for (int r = 0; r < 4; r++)
        esum += __builtin_amdgcn_exp2f(zz[r] * C1);
    }
  }

  esum += __shfl_xor(esum, 16);
  esum += __shfl_xor(esum, 32);
  if (lane < 16)
    dp[((size_t)z * 16 + bh) * SEQ + q0 + lane] = esum;
}

// ---------------------------------------------------------------------------
// Kernel 2b: fused attention (R7-proven store path): scores -> normalized p
// (bf16 LDS) -> attn store (256B-contiguous nontemporal f32x4) + PV.
// ASPLIT=4 -> 2048 blocks -> occupancy at the 5-block/CU LDS cap.
// ---------------------------------------------------------------------------
__global__ __launch_bounds__(256) void attn_pv_kernel(
    const short* __restrict__ Q, const short* __restrict__ K, const short* __restrict__ Vt,
    const float* __restrict__ dp, float* __restrict__ attn,
    short* __restrict__ ctxp0, short* __restrict__ ctxp3)
{
  __shared__ short Ks[64][72];
  __shared__ short Vs[64][72];
  __shared__ short P[4][16][72];

  int t = threadIdx.x, lane = t & 63, wave = t >> 6;
  int fr = lane & 15, fg = lane >> 4;
  int bh = blockIdx.y, z = blockIdx.z;
  const short* Qh = Q + (size_t)bh * SEQ * DK;
  const short* Kh = K + (size_t)bh * SEQ * DK;
  const short* Vh = Vt + (size_t)bh * DK * SEQ;
  int q0 = blockIdx.x * 64 + wave * 16;
  const int kbase = z * (SEQ / ASPLIT);

  short8 qa0 = *(const short8*)(Qh + (q0 + fr) * DK + fg * 8);
  short8 qa1 = *(const short8*)(Qh + (q0 + fr) * DK + 32 + fg * 8);

  float rden[4];
#pragma unroll
  for (int r = 0; r < 4; r++) {
    int row = q0 + fg * 4 + r;
    float d = 0.f;
#pragma unroll
    for (int zz = 0; zz < DSPLIT; zz++)
      d += dp[((size_t)zz * 16 + bh) * SEQ + row];
    rden[r] = 1.f / d;
  }

  int r_st = t >> 2, c_st = (t & 3) * 16;
  int rlo = lane >> 4, c4 = (lane & 15) * 4;

  f32x4 oacc[4] = {};

  const short* kp0 = Kh + (size_t)(kbase + r_st) * DK + c_st;
  const short* vp0 = Vh + (size_t)r_st * SEQ + kbase + c_st;
  short8 k_pf0 = *(const short8*)kp0;
  short8 k_pf1 = *(const short8*)(kp0 + 8);
  short8 v_pf0 = *(const short8*)vp0;
  short8 v_pf1 = *(const short8*)(vp0 + 8);

  for (int kt = 0; kt < NT_A; kt++) {
    int kb = kbase + kt * 64;
    __syncthreads();
    *(short8*)&Ks[r_st][c_st]     = k_pf0;
    *(short8*)&Ks[r_st][c_st + 8] = k_pf1;
    *(short8*)&Vs[r_st][c_st]     = v_pf0;
    *(short8*)&Vs[r_st][c_st + 8] = v_pf1;
    __syncthreads();
    if (kt + 1 < NT_A) {
      const short* kp = Kh + (size_t)(kb + 64 + r_st) * DK + c_st;
      const short* vp = Vh + (size_t)r_st * SEQ + kb + 64 + c_st;
      k_pf0 = *(const short8*)kp;
      k_pf1 = *(const short8*)(kp + 8);
      v_pf0 = *(const short8*)vp;
      v_pf1 = *(const short8*)(vp + 8);
    }

    // scores: 16 q-rows x 64 k-cols per wave (8 MFMAs, 4 independent chains)
    f32x4 sc[4];
#pragma unroll
    for (int ct = 0; ct < 4; ct++) {
      short8 k0v = *(const short8*)&Ks[ct * 16 + fr][fg * 8];
      short8 k1v = *(const short8*)&Ks[ct * 16 + fr][32 + fg * 8];
      f32x4 zz = {0.f, 0.f, 0.f, 0.f};
      zz = MFMA16(qa0, k0v, zz);
      zz = MFMA16(qa1, k1v, zz);
      sc[ct] = zz;
    }

    // exp + normalize -> bf16 P (feeds both the attn store and PV)
#pragma unroll
    for (int ct = 0; ct < 4; ct++)
#pragma unroll
      for (int r = 0; r < 4; r++) {
        float p = __expf(sc[ct][r] * 0.125f) * rden[r];
        P[wave][fg * 4 + r][ct * 16 + fr] = f2bf(p);
      }
    asm volatile("s_waitcnt lgkmcnt(0)" ::: "memory");

    // attn store: 4 instrs, each 4 rows x 256B contiguous, nontemporal
#pragma unroll
    for (int jr = 0; jr < 4; jr++) {
      int row = jr * 4 + rlo;
      short4v pv4 = *(const short4v*)&P[wave][row][c4];
      f32x4 vv = {bf2f(pv4[0]), bf2f(pv4[1]), bf2f(pv4[2]), bf2f(pv4[3])};
      __builtin_nontemporal_store(vv,
          (f32x4*)&attn[((size_t)(bh * SEQ + q0 + row)) * SEQ + kb + c4]);
    }

    // PV: oacc[dt] += P(16q x 64k) * V^T(64d x 64k); 8 MFMAs
    short8 pa0 = *(const short8*)&P[wave][fr][fg * 8];
    short8 pa1 = *(const short8*)&P[wave][fr][32 + fg * 8];
#pragma unroll
    for (int dt = 0; dt < 4; dt++) {
      short8 v0 = *(const short8*)&Vs[dt * 16 + fr][fg * 8];
      short8 v1 = *(const short8*)&Vs[dt * 16 + fr][32 + fg * 8];
      oacc[dt] = MFMA16(pa0, v0, oacc[dt]);
      oacc[dt] = MFMA16(pa1, v1, oacc[dt]);
    }
  }

  int b = bh >> 3, h = bh & 7;
  short* cbase = (z < 3) ? (ctxp0 + (size_t)z * NROWS * DM) : ctxp3;
#pragma unroll
  for (int dt = 0; dt < 4; dt++)
#pragma unroll
    for (int r = 0; r < 4; r++) {
      int row = q0 + fg * 4 + r;
      cbase[((size_t)b * SEQ + row) * DM + h * 64 + dt * 16 + fr] = f2bf(oacc[dt][r]);
    }
}

// ---------------------------------------------------------------------------
// Kernel 3: output projection + bias + residual -> x (f32).
// A-operand = sum of 4 normalized ctx partials (fused reduce, prefetched).
// ---------------------------------------------------------------------------
__global__ __launch_bounds__(256) void oproj_kernel(
    const short* __restrict__ ctxp0, const short* __restrict__ ctxp3,
    const short* __restrict__ Wob,
    const float* __restrict__ bias, const float* __restrict__ resid,
    float* __restrict__ xout)
{
  const size_t NPART = (size_t)NROWS * DM;
  __shared__ short As[64][40];
  __shared__ short Bs[64][40];

  int t = threadIdx.x;
  int lane = t & 63, wave = t >> 6;
  int wr = wave >> 1, wc = wave & 1;
  int fr = lane & 15, fg = lane >> 4;
  int m0 = blockIdx.x * 64, n0 = blockIdx.y * 64;
  int lrow = t >> 2, lcol = (t & 3) * 8;

  f32x4 acc[2][2] = {};

  size_t ia0 = (size_t)(m0 + lrow) * DM + lcol;
  short8 a_pf0 = *(const short8*)(ctxp0 + ia0);
  short8 a_pf1 = *(const short8*)(ctxp0 + NPART + ia0);
  short8 a_pf2 = *(const short8*)(ctxp0 + 2 * NPART + ia0);
  short8 a_pf3 = *(const short8*)(ctxp3 + ia0);
  short8 b_pf = *(const short8*)(Wob + (size_t)(n0 + lrow) * DM + lcol);

  for (int k0 = 0; k0 < DM; k0 += 32) {
    __syncthreads();
    {
      short8 sv;
#pragma unroll
      for (int j = 0; j < 8; j++)
        sv[j] = f2bf(bf2f(a_pf0[j]) + bf2f(a_pf1[j]) + bf2f(a_pf2[j]) + bf2f(a_pf3[j]));
      *(short8*)&As[lrow][lcol] = sv;
      *(short8*)&Bs[lrow][lcol] = b_pf;
    }
    __syncthreads();
    if (k0 + 32 < DM) {
      size_t ia = (size_t)(m0 + lrow) * DM + k0 + 32 + lcol;
      a_pf0 = *(const short8*)(ctxp0 + ia);
      a_pf1 = *(const short8*)(ctxp0 + NPART + ia);
      a_pf2 = *(const short8*)(ctxp0 + 2 * NPART + ia);
      a_pf3 = *(const short8*)(ctxp3 + ia);
      b_pf = *(const short8*)(Wob + (size_t)(n0 + lrow) * DM + k0 + 32 + lcol);
    }
    short8 a0 = *(const short8*)&As[wr * 32 + fr][fg * 8];
    short8 a1 = *(const short8*)&As[wr * 32 + 16 + fr][fg * 8];
    short8 b0 = *(const short8*)&Bs[wc * 32 + fr][fg * 8];
    short8 b1 = *(const short8*)&Bs[wc * 32 + 16 + fr][fg * 8];
    acc[0][0] = MFMA16(a0, b0, acc[0][0]);
    acc[0][1] = MFMA16(a0, b1, acc[0][1]);
    acc[1][0] = MFMA16(a1, b0, acc[1][0]);
    acc[1][1] = MFMA16(a1, b1, acc[1][1]);
  }

#pragma unroll
  for (int mi = 0; mi < 2; mi++)
#pragma unroll
    for (int ni = 0; ni < 2; ni++)
#pragma unroll
      for (int r = 0; r < 4; r++) {
        int row = m0 + wr * 32 + mi * 16 + fg * 4 + r;
        int col = n0 + wc * 32 + ni * 16 + fr;
        float val = acc[mi][ni][r] + bias[col] + resid[(size_t)row * DM + col];
        xout[(size_t)row * DM + col] = val;
      }
}

// ---------------------------------------------------------------------------
// Kernel 4: LayerNorm over last dim (512). One wave per row.
// ---------------------------------------------------------------------------
__global__ __launch_bounds__(256) void ln_kernel(
    const float* __restrict__ x, const float* __restrict__ gamma,
    const float* __restrict__ beta, float* __restrict__ y)
{
  int row = blockIdx.x * 4 + (threadIdx.x >> 6);
  int lane = threadIdx.x & 63;
  const float4* xr = (const float4*)(x + (size_t)row * DM);
  float4 v0 = xr[lane * 2];
  float4 v1 = xr[lane * 2 + 1];
  float s = v0.x + v0.y + v0.z + v0.w + v1.x + v1.y + v1.z + v1.w;
#pragma unroll
  for (int off = 1; off < 64; off <<= 1) s += __shfl_xor(s, off);
  float mean = s * (1.0f / DM);
  float a0 = v0.x - mean, a1 = v0.y - mean, a2 = v0.z - mean, a3 = v0.w - mean;
  float a4 = v1.x - mean, a5 = v1.y - mean, a6 = v1.z - mean, a7 = v1.w - mean;
  float vs = a0 * a0 + a1 * a1 + a2 * a2 + a3 * a3 + a4 * a4 + a5 * a5 + a6 * a6 + a7 * a7;
#pragma unroll
  for (int off = 1; off < 64; off <<= 1) vs += __shfl_xor(vs, off);
  float rstd = rsqrtf(vs * (1.0f / DM) + 1e-5f);
  const float4* gp = (const float4*)gamma;
  const float4* bp = (const float4*)beta;
  float4 g0 = gp[lane * 2], g1 = gp[lane * 2 + 1];
  float4 b0 = bp[lane * 2], b1 = bp[lane * 2 + 1];
  float4 o0, o1;
  o0.x = a0 * rstd * g0.x + b0.x; o0.y = a1 * rstd * g0.y + b0.y;
  o0.z = a2 * rstd * g0.z + b0.z; o0.w = a3 * rstd * g0.w + b0.w;
  o1.x = a4 * rstd * g1.x + b1.x; o1.y = a5 * rstd * g1.y + b1.y;
  o1.z = a6 * rstd * g1.z + b1.z; o1.w = a7 * rstd * g1.w + b1.w;
  float4* yr = (float4*)(y + (size_t)row * DM);
  yr[lane * 2] = o0;
  yr[lane * 2 + 1] = o1;
}

// ---------------------------------------------------------------------------
extern "C" void kernel_launch(void* const* d_in, const int* in_sizes, int n_in,
                              void* d_out, int out_size, void* d_ws, size_t ws_size,
                              hipStream_t stream)
{
  const float* q     = (const float*)d_in[0];
  const float* k     = (const float*)d_in[1];
  const float* v     = (const float*)d_in[2];
  const float* Wq    = (const float*)d_in[3];
  const float* bq    = (const float*)d_in[4];
  const float* Wk    = (const float*)d_in[5];
  const float* bk    = (const float*)d_in[6];
  const float* Wv    = (const float*)d_in[7];
  const float* bv    = (const float*)d_in[8];
  const float* Wo    = (const float*)d_in[9];
  const float* bo    = (const float*)d_in[10];
  const float* gamma = (const float*)d_in[11];
  const float* beta  = (const float*)d_in[12];

  char* w = (char*)d_ws;
  // [0,12): qbf/kbf/vbf (dead after qkv) -> reused as ctxp partials 0..2
  short* qbf  = (short*)(w);
  short* kbf  = (short*)(w + ((size_t)4  << 20));
  short* vbf  = (short*)(w + ((size_t)8  << 20));
  short* Qb   = (short*)(w + ((size_t)12 << 20));     // [12,16)  [B,H,S,DK]
  short* Kb   = (short*)(w + ((size_t)16 << 20));     // [16,20)
  short* Vtb  = (short*)(w + ((size_t)20 << 20));     // [20,24)  [B,H,DK,S]
  short* Wqb  = (short*)(w + ((size_t)24 << 20));     // [24,24.5)
  short* Wkb  = (short*)(w + ((size_t)24 << 20) + ((size_t)512 << 10));
  short* Wvb  = (short*)(w + ((size_t)25 << 20));
  short* Wob  = (short*)(w + ((size_t)25 << 20) + ((size_t)512 << 10));
  float* denp = (float*)(w + ((size_t)26 << 20));     // [26,26.5) f32 [4][16][SEQ]
  short* ctxp0 = (short*)(w);                         // [ 0,12): partials 0..2
  short* ctxp3 = (short*)(w + ((size_t)27 << 20));    // [27,31): partial 3
  float* xbuf  = (float*)(w + ((size_t)12 << 20));    // [12,20): reuse Qb/Kb (dead)

  float* y = (float*)d_out;
  float* attnp = y + (size_t)NROWS * DM;  // [B,H,S,S]

  cast3_kernel<<<dim3(1024, 1, 3), 256, 0, stream>>>(q, k, v, qbf, kbf, vbf);
  cast4_kernel<<<dim3(128, 1, 4), 256, 0, stream>>>(Wq, Wk, Wv, Wo, Wqb, Wkb, Wvb, Wob);
  qkv_proj_kernel<<<dim3(64, 8, 3), 256, 0, stream>>>(qbf, kbf, vbf, Wqb, Wkb, Wvb,
                                                      bq, bk, bv, Qb, Kb, Vtb);
  den_kernel<<<dim3(32, 16, DSPLIT), 256, 0, stream>>>(Qb, Kb, denp);
  attn_pv_kernel<<<dim3(32, 16, ASPLIT), 256, 0, stream>>>(Qb, Kb, Vtb, denp, attnp,
                                                           ctxp0, ctxp3);
  oproj_kernel<<<dim3(64, 8), 256, 0, stream>>>(ctxp0, ctxp3, Wob, bo, q, xbuf);
  ln_kernel<<<1024, 256, 0, stream>>>(xbuf, gamma, beta, y);
}